// Round 1
// baseline (161.262 us; speedup 1.0000x reference)
//
#include <hip/hip_runtime.h>

// B=262144 x C=101 fp32 -> 3 scalars.
//
// R7: DPP + vectorized streaming. R6 (scalar dword loads + shuffle-based
// reduce) converged to ~44us = 2.3 TB/s: the hot loop issued 7 scalar
// VMEM + ~29 ds_swizzle/bpermute per 4-row group, a serial lgkm chain
// that 4 waves/SIMD can't hide. R7 keeps the 4-teams-of-16 structure but:
//   * lane s owns j = 8s..8s+7 (contiguous): 2 predicated dwordx4 + 1 tail
//     dword per group (rows are 404B = 4B-aligned, so loads use an
//     aligned(4) ext-vector; HW unaligned mode emits dwordx4 either way).
//   * 16-lane team == DPP row: team reduce = 4x v_add row_shr:{1,2,4,8}
//     (VALU pipe, zero DS traffic); penalty seam e_{j+1} via row_shl:1
//     with bound_ctrl=1 (lane 15 reads 0 = exactly the zero-pad semantics).
//   * pen = sum_j max(e_j - e_{j+1}, 0) - e_t with e_j := 0 for j >= 101
//     (identity validated R4/R5, absmax 0).
//   * 2048 blocks (8 waves/SIMD) x contiguous 8-group chunks per wave:
//     32 rows x 404B = 101 full 128B lines per wave -> no line sharing
//     across waves/XCDs.

#define NC 101
#define LAMBDA_W 1000.0

typedef float f4a __attribute__((ext_vector_type(4), aligned(4)));

// sum of the 16-lane team (DPP row); total lands in lane 15 of each row
__device__ __forceinline__ float team_sum16(float v) {
    v += __int_as_float(__builtin_amdgcn_update_dpp(
        0, __float_as_int(v), 0x111, 0xf, 0xf, true)); // row_shr:1
    v += __int_as_float(__builtin_amdgcn_update_dpp(
        0, __float_as_int(v), 0x112, 0xf, 0xf, true)); // row_shr:2
    v += __int_as_float(__builtin_amdgcn_update_dpp(
        0, __float_as_int(v), 0x114, 0xf, 0xf, true)); // row_shr:4
    v += __int_as_float(__builtin_amdgcn_update_dpp(
        0, __float_as_int(v), 0x118, 0xf, 0xf, true)); // row_shr:8
    return v;
}

// lane s gets lane s+1's value within the 16-lane team; lane 15 gets 0
__device__ __forceinline__ float team_next(float v) {
    return __int_as_float(__builtin_amdgcn_update_dpp(
        0, __float_as_int(v), 0x101, 0xf, 0xf, true)); // row_shl:1, bound_ctrl
}

__global__ __launch_bounds__(256)
void ucl_stream_kernel(const float* __restrict__ x,
                       const int* __restrict__ tgt,
                       float2* __restrict__ partial,
                       int ngroups)              // B/4 row-groups
{
    const int tid  = threadIdx.x;
    const int lane = tid & 63;
    const int s    = lane & 15;                  // slot within team
    const int gwave  = blockIdx.x * 4 + (tid >> 6);
    const int nwaves = gridDim.x * 4;

    // per-lane column constants: j = 8s + i
    const int jbase = 8 * s;
    float fj[8];
#pragma unroll
    for (int i = 0; i < 8; ++i) fj[i] = (float)(jbase + i);

    float conc = 0.f, pens = 0.f;

    // contiguous chunk per wave (line-aligned span: 8 groups = 101 lines)
    const int per = ngroups / nwaves;
    const int rem = ngroups - per * nwaves;
    const int cnt  = per + (gwave < rem ? 1 : 0);
    const int base = gwave * per + (gwave < rem ? gwave : rem);

    for (int it = 0; it < cnt; ++it) {
        const int g   = base + it;
        const int row = g * 4 + (lane >> 4);     // team's row
        const float* __restrict__ xr = x + (size_t)row * NC;
        const int t = tgt[row];                  // broadcast within team

        // ---- predicated vector loads, j = 8s..8s+7 ----
        f4a va = {0.f, 0.f, 0.f, 0.f};
        f4a vb = {0.f, 0.f, 0.f, 0.f};
        if (s < 13) va = *(const f4a*)(xr + jbase);        // j..j+3 <= 99
        if (s < 12) vb = *(const f4a*)(xr + jbase + 4);    // j+4..j+7 <= 95
        else if (s == 12) vb.x = xr[100];                  // lone e_100

        // ---- exp; force 0 (not exp(0)=1) on padded slots ----
        float e[8];
#pragma unroll
        for (int i = 0; i < 4; ++i) {
            float ea = __expf(va[i]);
            float eb = __expf(vb[i]);
            e[i]     = (s < 13) ? ea : 0.f;
            e[4 + i] = (s < (i == 0 ? 13 : 12)) ? eb : 0.f;
        }

        // ---- moments (all in-lane) ----
        float S = 0.f, W = 0.f, Q = 0.f;
#pragma unroll
        for (int i = 0; i < 8; ++i) {
            float p = e[i] * fj[i];
            S += e[i];
            W += p;
            Q  = fmaf(p, fj[i], Q);
        }

        // ---- penalty: d_j = e_j - e_{j+1}, e_{101..} = 0 ----
        const float en = team_next(e[0]);        // e_{8(s+1)}; 0 at s==15
        float pen = 0.f;
#pragma unroll
        for (int i = 0; i < 8; ++i) {
            float nx = (i < 7) ? e[i + 1] : en;
            pen += fmaxf(e[i] - nx, 0.f);
            pen -= (jbase + i == t) ? e[i] : 0.f;  // -e_t by owner
        }

        // ---- team reduce on the VALU pipe (DPP, zero DS ops) ----
        S   = team_sum16(S);
        W   = team_sum16(W);
        Q   = team_sum16(Q);
        pen = team_sum16(pen);

        if (s == 15) {                           // row total lives in lane 15
            float pred = W / S;
            float var  = fmaxf(fmaf(-pred, pred, Q / S), 1e-6f);
            float err  = pred - (float)t;
            conc += 0.5f * __logf(var) + err * err / (2.0f * var);
            pens += pen / S;
        }
    }

    // ---- wave reduce (values at lanes 15,31,47,63) ----
    conc += __shfl_down(conc, 16);
    pens += __shfl_down(pens, 16);
    conc += __shfl_down(conc, 32);
    pens += __shfl_down(pens, 32);

    __shared__ float red[8];
    if (lane == 15) {
        red[(tid >> 6) * 2 + 0] = conc;
        red[(tid >> 6) * 2 + 1] = pens;
    }
    __syncthreads();
    if (tid == 0)
        partial[blockIdx.x] = make_float2(red[0] + red[2] + red[4] + red[6],
                                          red[1] + red[3] + red[5] + red[7]);
}

__global__ __launch_bounds__(256)
void ucl_finalize(const float2* __restrict__ partial,
                  float* __restrict__ out,
                  int nblocks, double invB)
{
    const int tid = threadIdx.x;
    double c = 0.0, p = 0.0;
    for (int i = tid; i < nblocks; i += 256) {
        float2 v = partial[i];
        c += (double)v.x;
        p += (double)v.y;
    }
#pragma unroll
    for (int off = 32; off > 0; off >>= 1) {
        c += __shfl_down(c, off);
        p += __shfl_down(p, off);
    }
    __shared__ double sm[8];
    if ((tid & 63) == 0) { sm[(tid >> 6) * 2] = c; sm[(tid >> 6) * 2 + 1] = p; }
    __syncthreads();
    if (tid == 0) {
        double C = (sm[0] + sm[2] + sm[4] + sm[6]) * invB;
        double P = (sm[1] + sm[3] + sm[5] + sm[7]) * invB * LAMBDA_W;
        out[0] = (float)(C + P);
        out[1] = (float)C;
        out[2] = (float)P;
    }
}

extern "C" void kernel_launch(void* const* d_in, const int* in_sizes, int n_in,
                              void* d_out, int out_size, void* d_ws, size_t ws_size,
                              hipStream_t stream)
{
    const float* x   = (const float*)d_in[0];
    const int*   tgt = (const int*)d_in[1];
    float* out = (float*)d_out;
    float2* partial = (float2*)d_ws;

    const int B = in_sizes[1];        // 262144
    const int ngroups = B / 4;        // 65536
    const int blocks = 2048;          // 8 waves/SIMD target

    hipLaunchKernelGGL(ucl_stream_kernel, dim3(blocks), dim3(256), 0, stream,
                       x, tgt, partial, ngroups);
    hipLaunchKernelGGL(ucl_finalize, dim3(1), dim3(256), 0, stream,
                       partial, out, blocks, 1.0 / (double)B);
}

// Round 3
// 154.883 us; speedup vs baseline: 1.0412x; 1.0412x over previous
//
#include <hip/hip_runtime.h>

// B=262144 x C=101 fp32 -> 3 scalars.
//
// R8 (resubmit; R2 bench was an infra failure, not a kernel failure):
// R6 structure EXACTLY (grid-stride, 1024 blocks, team-of-16 per row,
// 7 aligned scalar dword loads j = s+16k) with ONE change: every hot-loop
// cross-lane shuffle (29 ds_swizzle/ds_bpermute per 4-row group on the
// shared LDS pipe) is replaced by DPP on the VALU pipe:
//   * team reduce: v_add row_shr:{1,2,4,8}, row total lands in lane 15
//     (standard DPP scan; HW-validated in R7, absmax 0).
//   * penalty neighbor e_{j+1}: row_shl:1 (lane s <- lane s+1; lane 15
//     zero-filled by bound_ctrl, then overridden by the seam value).
//   * seam (lane 15 needs lane 0's e[k+1] = e_{16(k+1)}): row_shr:15
//     (dst lane 15 <- src lane 0; only lane 15 consumes it).
// R7 post-mortem: misaligned dwordx4 (404 B row stride) + contiguous-chunk
// scheduling regressed 153.9->161.3; both reverted here. DPP math is
// identical to R6's shuffle math (R6/R7 both absmax 0).
//
// pen = sum_j max(e_j - e_{j+1}, 0) - e_t with e_j := 0 for j >= 101
// (zero-pad absorbs the +e_100 term; identity validated R4/R5).

#define NC 101
#define LAMBDA_W 1000.0

template <int CTRL>
__device__ __forceinline__ float dpp_mov(float v) {
    // bound_ctrl=true: out-of-row source lanes produce 0
    return __int_as_float(__builtin_amdgcn_update_dpp(
        0, __float_as_int(v), CTRL, 0xf, 0xf, true));
}

// sum of the 16-lane team (DPP row); total lands in lane 15 of each row
__device__ __forceinline__ float team_sum16(float v) {
    v += dpp_mov<0x111>(v);   // row_shr:1
    v += dpp_mov<0x112>(v);   // row_shr:2
    v += dpp_mov<0x114>(v);   // row_shr:4
    v += dpp_mov<0x118>(v);   // row_shr:8
    return v;
}

__global__ __launch_bounds__(256)
void ucl_stream_kernel(const float* __restrict__ x,
                       const int* __restrict__ tgt,
                       float2* __restrict__ partial,
                       int ngroups)              // B/4 row-groups
{
    const int tid  = threadIdx.x;
    const int lane = tid & 63;
    const int s    = lane & 15;                  // slot within team
    const int gwave  = blockIdx.x * 4 + (tid >> 6);
    const int nwaves = gridDim.x * 4;

    const float fs = (float)s;
    float conc = 0.f, pens = 0.f;

    for (int g = gwave; g < ngroups; g += nwaves) {
        const int row = g * 4 + (lane >> 4);     // team's row
        const float* __restrict__ xr = x + (size_t)row * NC;
        const int t = tgt[row];                  // broadcast within team

        // ---- hoisted predicated loads, j = s + 16k (always 4B-aligned) ----
        float e[7];
#pragma unroll
        for (int k = 0; k < 7; ++k) {
            const int j = s + 16 * k;
            e[k] = (j < NC) ? xr[j] : 0.f;
        }
        // exp; force 0 (not exp(0)=1) on padded lanes
#pragma unroll
        for (int k = 0; k < 7; ++k) {
            const int j = s + 16 * k;
            float ee = __expf(e[k]);
            e[k] = (j < NC) ? ee : 0.f;
        }

        // ---- moments ----
        float S = 0.f, W = 0.f, Q = 0.f;
#pragma unroll
        for (int k = 0; k < 7; ++k) {
            const float fj = fs + (float)(16 * k);
            S += e[k];
            W = fmaf(e[k], fj, W);
            Q = fmaf(e[k], fj * fj, Q);
        }

        // ---- penalty: d_j = e_j - e_{j+1} (e_{101..} = 0), all on VALU ----
        float pen = 0.f;
#pragma unroll
        for (int k = 0; k < 7; ++k) {
            float n1 = dpp_mov<0x101>(e[k]);               // row_shl:1 -> e_{j+1}, 0 at s==15
            float nx = (k < 6) ? dpp_mov<0x11F>(e[k + 1])  // row_shr:15 -> lane15 gets lane0's e[k+1]
                               : 0.f;
            float en = (s == 15) ? nx : n1;
            float d  = e[k] - en;
            pen += fmaxf(d, 0.f);
            const int j = s + 16 * k;
            pen -= (j == t) ? e[k] : 0.f;                  // -e_t by owner
        }

        // ---- team reduce on the VALU pipe (zero DS ops) ----
        S   = team_sum16(S);
        W   = team_sum16(W);
        Q   = team_sum16(Q);
        pen = team_sum16(pen);

        if (s == 15) {                           // row total lives in lane 15
            float pred = W / S;
            float var  = fmaxf(fmaf(-pred, pred, Q / S), 1e-6f);
            float err  = pred - (float)t;
            conc += 0.5f * __logf(var) + err * err / (2.0f * var);
            pens += pen / S;
        }
    }

    // ---- wave reduce (values at lanes 15,31,47,63) ----
    conc += __shfl_down(conc, 16);
    pens += __shfl_down(pens, 16);
    conc += __shfl_down(conc, 32);
    pens += __shfl_down(pens, 32);

    __shared__ float red[8];
    if (lane == 15) {
        red[(tid >> 6) * 2 + 0] = conc;
        red[(tid >> 6) * 2 + 1] = pens;
    }
    __syncthreads();
    if (tid == 0)
        partial[blockIdx.x] = make_float2(red[0] + red[2] + red[4] + red[6],
                                          red[1] + red[3] + red[5] + red[7]);
}

__global__ __launch_bounds__(256)
void ucl_finalize(const float2* __restrict__ partial,
                  float* __restrict__ out,
                  int nblocks, double invB)
{
    const int tid = threadIdx.x;
    double c = 0.0, p = 0.0;
    for (int i = tid; i < nblocks; i += 256) {
        float2 v = partial[i];
        c += (double)v.x;
        p += (double)v.y;
    }
#pragma unroll
    for (int off = 32; off > 0; off >>= 1) {
        c += __shfl_down(c, off);
        p += __shfl_down(p, off);
    }
    __shared__ double sm[8];
    if ((tid & 63) == 0) { sm[(tid >> 6) * 2] = c; sm[(tid >> 6) * 2 + 1] = p; }
    __syncthreads();
    if (tid == 0) {
        double C = (sm[0] + sm[2] + sm[4] + sm[6]) * invB;
        double P = (sm[1] + sm[3] + sm[5] + sm[7]) * invB * LAMBDA_W;
        out[0] = (float)(C + P);
        out[1] = (float)C;
        out[2] = (float)P;
    }
}

extern "C" void kernel_launch(void* const* d_in, const int* in_sizes, int n_in,
                              void* d_out, int out_size, void* d_ws, size_t ws_size,
                              hipStream_t stream)
{
    const float* x   = (const float*)d_in[0];
    const int*   tgt = (const int*)d_in[1];
    float* out = (float*)d_out;
    float2* partial = (float2*)d_ws;

    const int B = in_sizes[1];        // 262144
    const int ngroups = B / 4;        // 65536
    const int blocks = 1024;

    hipLaunchKernelGGL(ucl_stream_kernel, dim3(blocks), dim3(256), 0, stream,
                       x, tgt, partial, ngroups);
    hipLaunchKernelGGL(ucl_finalize, dim3(1), dim3(256), 0, stream,
                       partial, out, blocks, 1.0 / (double)B);
}